// Round 1
// baseline (134.466 us; speedup 1.0000x reference)
//
#include <hip/hip_runtime.h>

#define TDIM 1024
#define KDIM 32

// One step of the linear-space CRF recurrence.
// a (per-lane, lane j holds a[j], duplicated across wave halves) ->
// new_a[j] = (sum_i a[i] * E[i][j]) * exp(emis_raw) * 2^{-e0},  tote += e0
__device__ __forceinline__ float crf_step(float a, float eraw, const float E[KDIM], int& tote)
{
    // broadcast a[0] first for the scale factor (off the critical FMA chain)
    float s0 = __int_as_float(__builtin_amdgcn_readlane(__float_as_int(a), 0));
    unsigned b0 = __float_as_uint(s0);
    int e0 = (int)((b0 >> 23) & 255u) - 127;
    tote += e0;
    float sf = __uint_as_float((unsigned)(127 - e0) << 23);  // exact 2^-e0
    float ev = __expf(eraw) * sf;

    float acc0 = 0.0f, acc1 = 0.0f, acc2 = 0.0f, acc3 = 0.0f;
#pragma unroll
    for (int i = 0; i < KDIM; i += 4) {
        float a0 = __int_as_float(__builtin_amdgcn_readlane(__float_as_int(a), i + 0));
        float a1 = __int_as_float(__builtin_amdgcn_readlane(__float_as_int(a), i + 1));
        float a2 = __int_as_float(__builtin_amdgcn_readlane(__float_as_int(a), i + 2));
        float a3 = __int_as_float(__builtin_amdgcn_readlane(__float_as_int(a), i + 3));
        acc0 = fmaf(a0, E[i + 0], acc0);
        acc1 = fmaf(a1, E[i + 1], acc1);
        acc2 = fmaf(a2, E[i + 2], acc2);
        acc3 = fmaf(a3, E[i + 3], acc3);
    }
    return ((acc0 + acc1) + (acc2 + acc3)) * ev;
}

__global__ __launch_bounds__(64) void crf_partition_kernel(
    const float* __restrict__ emissions,     // [B, T, K]
    const int*   __restrict__ lengths32,     // [B] (int32 or int64 low/high words)
    const float* __restrict__ transitions,   // [K, K]
    const float* __restrict__ head_t,        // [K]
    const float* __restrict__ last_t,        // [K]
    float*       __restrict__ out)           // [B]
{
    const int b    = blockIdx.x;
    const int lane = threadIdx.x;
    const int j    = lane & 31;

    // int64 vs int32 lengths: if int64 little-endian, the int32 view at odd
    // index 1 is the high word of lengths[0] == 0 (values are 1..1024).
    // If int32, lengths[1] is in [1,1024], never 0.
    const bool is64 = (lengths32[1] == 0);
    int len = is64 ? lengths32[2 * b] : lengths32[b];
    len = len < 1 ? 1 : (len > TDIM ? TDIM : len);

    const float* erow = emissions + (size_t)b * TDIM * KDIM + j;

    // E[i] = exp(transitions[i][j]) : lane j holds column j
    float E[KDIM];
#pragma unroll
    for (int i = 0; i < KDIM; ++i)
        E[i] = __expf(transitions[i * KDIM + j]);

    // t = 0 init: chart0 = head + emissions[:,0,:]
    float na = __expf(head_t[j] + erow[0]);
    int tote = 0;

    // emission prefetch pipeline, depth 8 (registers, static indices only)
    float cur[8], nxt[8];
#pragma unroll
    for (int u = 0; u < 8; ++u) {
        int tt = 1 + u; tt = tt > (TDIM - 1) ? (TDIM - 1) : tt;   // clamp (unused slots read garbage safely in-bounds)
        cur[u] = erow[tt * KDIM];
    }

    int t = 1;
    for (; t + 8 <= len; t += 8) {
        // prefetch t+8 .. t+15
#pragma unroll
        for (int u = 0; u < 8; ++u) {
            int tt = t + 8 + u; tt = tt > (TDIM - 1) ? (TDIM - 1) : tt;
            nxt[u] = erow[tt * KDIM];
        }
#pragma unroll
        for (int u = 0; u < 8; ++u)
            na = crf_step(na, cur[u], E, tote);
#pragma unroll
        for (int u = 0; u < 8; ++u)
            cur[u] = nxt[u];
    }

    // tail: steps t .. len-1 (cur[] already holds emissions for t..t+7)
    const int rem = len - t;  // 0..7, wave-uniform
#pragma unroll
    for (int u = 0; u < 8; ++u) {
        if (u < rem)
            na = crf_step(na, cur[u], E, tote);
    }

    // finalize: out[b] = log(sum_j a[j] * exp(last[j])) + tote*ln2
    float p = na * __expf(last_t[j]);
#pragma unroll
    for (int m = 16; m >= 1; m >>= 1)
        p += __shfl_xor(p, m, 64);

    if (lane == 0)
        out[b] = __logf(p) + (float)tote * 0.69314718055994531f;
}

extern "C" void kernel_launch(void* const* d_in, const int* in_sizes, int n_in,
                              void* d_out, int out_size, void* d_ws, size_t ws_size,
                              hipStream_t stream)
{
    const float* emissions   = (const float*)d_in[0];
    const int*   lengths     = (const int*)d_in[1];
    const float* transitions = (const float*)d_in[2];
    const float* head_t      = (const float*)d_in[3];
    const float* last_t      = (const float*)d_in[4];
    float* out = (float*)d_out;

    const int B = out_size;  // 512
    crf_partition_kernel<<<B, 64, 0, stream>>>(emissions, lengths, transitions,
                                               head_t, last_t, out);
}

// Round 2
// 72.784 us; speedup vs baseline: 1.8475x; 1.8475x over previous
//
#include <hip/hip_runtime.h>
#include <hip/hip_bf16.h>

#define TDIM 1024
#define KDIM 32
#define CH_S 128          // steps per chunk
#define NCHUNK 8          // TDIM / CH_S

typedef short bf16x8 __attribute__((ext_vector_type(8)));
typedef float f32x4  __attribute__((ext_vector_type(4)));

__device__ __forceinline__ unsigned short f2bf(float x) {
    __hip_bfloat16 h = __float2bfloat16(x);
    return *reinterpret_cast<unsigned short*>(&h);
}

__device__ __forceinline__ int read_len(const int* __restrict__ lengths32, int b) {
    // int64 little-endian: int32 view at odd index 1 is high word of lengths[0] == 0.
    // int32: lengths[1] in [1,1024], never 0.  (verified passing in round 1)
    const bool is64 = (lengths32[1] == 0);
    int len = is64 ? lengths32[2 * b] : lengths32[b];
    return len < 1 ? 1 : (len > TDIM ? TDIM : len);
}

// ---------------- K1: per-(batch, chunk) 32x32 product matrix -------------
// P_chunk = prod_{t in [1+c*S, min(1+(c+1)S, len)) } E^T D_t   (D_t = diag(exp(emis_t)))
// Stored bf16, col-major (addr = col*32+row), with integer power-of-2 scale ledger.
__global__ __launch_bounds__(64) void crf_chunk_kernel(
    const float* __restrict__ emissions,    // [B, T, K]
    const int*   __restrict__ lengths32,
    const float* __restrict__ transitions,  // [K, K]
    unsigned int* __restrict__ Pout,        // [B][NCHUNK][1024] bf16 packed as 512 dwords
    int*          __restrict__ toteOut)     // [B][NCHUNK]
{
    const int c    = blockIdx.x;
    const int b    = blockIdx.y;
    const int lane = threadIdx.x;
    const int n    = lane & 15;   // tile col / A row (local)
    const int g    = lane >> 4;   // lane group 0..3
    const int j32  = lane & 31;

    const int len    = read_len(lengths32, b);
    const int tstart = 1 + c * CH_S;
    int count = len - tstart; if (count > CH_S) count = CH_S;
    if (count <= 0) return;                       // dead chunk

    // slot -> contraction-row map: rho(g,e) = e<4 ? 4g+e : 16+4g+(e-4)
    int rho[8];
#pragma unroll
    for (int e = 0; e < 8; ++e) rho[e] = (e < 4) ? (4 * g + e) : (16 + 4 * g + (e - 4));

    // Static A-frags: A_I elem e = E^T[16I+n][rho] = exp(trans[rho][16I+n])
    bf16x8 A0, A1;
#pragma unroll
    for (int e = 0; e < 8; ++e) {
        A0[e] = (short)f2bf(__expf(transitions[rho[e] * KDIM + n]));
        A1[e] = (short)f2bf(__expf(transitions[rho[e] * KDIM + 16 + n]));
    }

    // bpermute byte-addrs for ev distribution (src lane = rho)
    int bpa[8];
#pragma unroll
    for (int e = 0; e < 8; ++e) bpa[e] = rho[e] * 4;

    // P = Identity in C-frags: tile(I,J) reg q: row=16I+4g+q, col=16J+n
    f32x4 C00, C01, C10, C11;
#pragma unroll
    for (int q = 0; q < 4; ++q) {
        float d = (4 * g + q == n) ? 1.0f : 0.0f;
        C00[q] = d; C11[q] = d; C01[q] = 0.0f; C10[q] = 0.0f;
    }

    const float* eptr = emissions + (size_t)b * TDIM * KDIM + j32;
    int   tote = 0, s_i = 0;
    float s_f  = 0.0f;
    const f32x4 zero = {0.0f, 0.0f, 0.0f, 0.0f};

    auto STEP = [&](float eraw) {
        tote += s_i;
        // ev = exp(e_t) * 2^-s  (approx; ledger compensated, error ~1e-7/step)
        float ev = __expf(fmaf(s_f, -0.69314718055994531f, eraw));
        float evd[8];
#pragma unroll
        for (int e = 0; e < 8; ++e)
            evd[e] = __int_as_float(__builtin_amdgcn_ds_bpermute(bpa[e], __float_as_int(ev)));
        // B_J slot e = ev[rho]*P[rho][16J+n]  == scaled C values of THIS lane
        bf16x8 B0, B1;
#pragma unroll
        for (int q = 0; q < 4; ++q) {
            B0[q]     = (short)f2bf(C00[q] * evd[q]);
            B0[q + 4] = (short)f2bf(C10[q] * evd[q + 4]);
            B1[q]     = (short)f2bf(C01[q] * evd[q]);
            B1[q + 4] = (short)f2bf(C11[q] * evd[q + 4]);
        }
        C00 = __builtin_amdgcn_mfma_f32_16x16x32_bf16(A0, B0, zero, 0, 0, 0);
        C01 = __builtin_amdgcn_mfma_f32_16x16x32_bf16(A0, B1, zero, 0, 0, 0);
        C10 = __builtin_amdgcn_mfma_f32_16x16x32_bf16(A1, B0, zero, 0, 0, 0);
        C11 = __builtin_amdgcn_mfma_f32_16x16x32_bf16(A1, B1, zero, 0, 0, 0);
        // next-step scale from P[0][0] (lane 0, C00 reg 0); P00 kept ~1 => safe
        int bits = __builtin_amdgcn_readfirstlane(__float_as_int(C00[0]));
        s_i = ((bits >> 23) & 255) - 127;
        s_f = (float)s_i;
    };

    // emission prefetch pipeline, depth 4
    float epf[4];
#pragma unroll
    for (int u = 0; u < 4; ++u) {
        int t = tstart + u; t = t > (TDIM - 1) ? (TDIM - 1) : t;
        epf[u] = eptr[t * KDIM];
    }
    int i = 0;
    for (; i + 4 <= count; i += 4) {
#pragma unroll
        for (int u = 0; u < 4; ++u) {
            STEP(epf[u]);
            int tn = tstart + i + u + 4; tn = tn > (TDIM - 1) ? (TDIM - 1) : tn;
            epf[u] = eptr[tn * KDIM];
        }
    }
#pragma unroll
    for (int u = 0; u < 4; ++u)
        if (u < count - i) STEP(epf[u]);

    // store bf16 col-major: dword idx = col*16 + row/2  (rows paired q,q+1)
    unsigned int* outP = Pout + ((size_t)b * NCHUNK + c) * 512;
#pragma unroll
    for (int p = 0; p < 2; ++p) {
        int q = 2 * p;
        outP[n * 16        + (4 * g + q) / 2]       = (unsigned)f2bf(C00[q]) | ((unsigned)f2bf(C00[q + 1]) << 16);
        outP[(16 + n) * 16 + (4 * g + q) / 2]       = (unsigned)f2bf(C01[q]) | ((unsigned)f2bf(C01[q + 1]) << 16);
        outP[n * 16        + (16 + 4 * g + q) / 2]  = (unsigned)f2bf(C10[q]) | ((unsigned)f2bf(C10[q + 1]) << 16);
        outP[(16 + n) * 16 + (16 + 4 * g + q) / 2]  = (unsigned)f2bf(C11[q]) | ((unsigned)f2bf(C11[q + 1]) << 16);
    }
    if (lane == 0) toteOut[b * NCHUNK + c] = tote;
}

// ---------------- K2: chain chunk matrices through alpha ------------------
__global__ __launch_bounds__(64) void crf_combine_kernel(
    const float* __restrict__ emissions,
    const int*   __restrict__ lengths32,
    const float* __restrict__ head_t,
    const float* __restrict__ last_t,
    const unsigned short* __restrict__ Pbuf,  // [B][NCHUNK][1024] bf16 col-major
    const int*   __restrict__ toteBuf,
    float*       __restrict__ out)
{
    __shared__ unsigned short Plds[NCHUNK * 1024];   // 16 KB
    const int b    = blockIdx.x;
    const int lane = threadIdx.x;
    const int j    = lane & 31;

    const int len = read_len(lengths32, b);
    int nAlive = (len - 1 + CH_S - 1) / CH_S;
    if (nAlive > NCHUNK) nAlive = NCHUNK;

    // stage alive chunk matrices to LDS (uint4 = 8 bf16 per load)
    const uint4* src = (const uint4*)(Pbuf + (size_t)b * NCHUNK * 1024);
    uint4* dst = (uint4*)Plds;
    for (int idx = lane; idx < nAlive * 128; idx += 64) dst[idx] = src[idx];

    float alpha = __expf(head_t[j] + emissions[(size_t)b * TDIM * KDIM + j]);
    int tote = 0;

    for (int cix = 0; cix < nAlive; ++cix) {
        const unsigned short* P = Plds + cix * 1024;
        float acc = 0.0f;
#pragma unroll
        for (int kk = 0; kk < KDIM; ++kk) {
            float pij = __uint_as_float((unsigned)P[kk * KDIM + j] << 16);   // P[row=j][col=kk]
            float ak  = __int_as_float(__builtin_amdgcn_readlane(__float_as_int(alpha), kk));
            acc = fmaf(pij, ak, acc);
        }
        // rescale alpha to ~1 (power of 2, exact, ledgered)
        int bits = __builtin_amdgcn_readfirstlane(__float_as_int(acc));
        int s = ((bits >> 23) & 255) - 127;
        alpha = acc * __uint_as_float((unsigned)(127 - s) << 23);
        tote += s + toteBuf[b * NCHUNK + cix];
    }

    float p = alpha * __expf(last_t[j]);
#pragma unroll
    for (int m = 16; m >= 1; m >>= 1)
        p += __shfl_xor(p, m, 64);

    if (lane == 0)
        out[b] = __logf(p) + (float)tote * 0.69314718055994531f;
}

extern "C" void kernel_launch(void* const* d_in, const int* in_sizes, int n_in,
                              void* d_out, int out_size, void* d_ws, size_t ws_size,
                              hipStream_t stream)
{
    const float* emissions   = (const float*)d_in[0];
    const int*   lengths     = (const int*)d_in[1];
    const float* transitions = (const float*)d_in[2];
    const float* head_t      = (const float*)d_in[3];
    const float* last_t      = (const float*)d_in[4];
    float* out = (float*)d_out;
    const int B = out_size;  // 512

    // workspace: P matrices (bf16) then tote ledger
    unsigned int* Pbuf   = (unsigned int*)d_ws;                       // B*NCHUNK*512 dwords = 8 MB
    int*          toteBf = (int*)((char*)d_ws + (size_t)B * NCHUNK * 2048);

    dim3 g1(NCHUNK, B);
    crf_chunk_kernel<<<g1, 64, 0, stream>>>(emissions, lengths, transitions, Pbuf, toteBf);
    crf_combine_kernel<<<B, 64, 0, stream>>>(emissions, lengths, head_t, last_t,
                                             (const unsigned short*)Pbuf, toteBf, out);
}